// Round 2
// baseline (280.872 us; speedup 1.0000x reference)
//
#include <hip/hip_runtime.h>
#include <hip/hip_fp16.h>

// GridSmoother: per-(batch,channel) CG solve of (I + graph-Laplacian) x = b
// on a 128x160 grid. One workgroup (1024 threads = 16 waves) per system;
// 256 systems = 256 workgroups = 1 per CU. CG vectors p/r/Ap in registers,
// x in LDS (conflict-free [k][tid] layout); wave-edge column halos +
// reduction slots in LDS.
//
// Round-3 changes vs round-2 (147 us/dispatch, VGPR=64, FETCH 75.6 MB):
//  * __launch_bounds__(1024, 1): round-2's (1024, 4) was interpreted as
//    min-4-BLOCKS/CU (CUDA semantics) -> 8 waves/SIMD -> 64-VGPR cap ->
//    ~40 regs/thread spilled (hbm_bytes doubled: 75.6 MB FETCH / 58 MB WRITE
//    = scratch traffic). (1024, 1) -> 1 block/CU -> 2048-reg pool / 16 waves
//    = 128-VGPR cap; live state ~105 regs fits with zero spill.
//    Evidence: (512,2) gave 128 cap (2 blk x 8 waves = 4 waves/SIMD).
//  * 2 barriers/iteration instead of 3: p-halo exchange is reconstructed
//    locally. p_new = r + beta*p_old with block-uniform beta, so each wave
//    updates its REGISTER copy of the neighbour p-edges from the neighbour
//    r-edges (published alongside the rr reduction, sharing barrier B).
//    Stencil no longer reads halos from LDS at all.
//  * Final iteration skips the dead tail (rr reduce / beta / p update).
//
// Thread mapping: lane l holds rows 2l,2l+1 (wave spans all 128 rows);
// wave w holds columns [10w, 10w+10). Up/down neighbors: own register or
// __shfl +-1 lane. Left/right: own registers except wave edges (register
// halo pairs hlp/hrp, refreshed from LDS r-edges once per iteration).
// Weights packed fp16 (pairs per column) to fit the VGPR budget.

#define GH 128
#define GW 160
#define NW 16
#define NCOL 10
#define NT 1024
#define NITER 16

__device__ __forceinline__ float wave_sum(float v) {
  #pragma unroll
  for (int off = 32; off > 0; off >>= 1) v += __shfl_xor(v, off, 64);
  return v;
}

// Stencil: Ap = c + wxl*(c-left) + wxr*(c-right) + wyu*(c-up) + wyd*(c-down)
// Boundary terms vanish because the corresponding weight regs are zeroed.
// Left/right neighbours at wave edges come from register halos hlp/hrp.
// ACCUM may use c0,c1 (p values) and a0,a1 (Ap values).
#define STENCIL(ACCUM)                                                        \
  {                                                                           \
    float lf0 = hlp.x, lf1 = hlp.y;                                           \
    float wxl0 = __low2float(wxlh), wxl1 = __high2float(wxlh);                \
    _Pragma("unroll")                                                         \
    for (int k = 0; k < NCOL; ++k) {                                          \
      const float c0 = p0[k], c1 = p1[k];                                     \
      const float rt0 = (k == NCOL - 1) ? hrp.x : p0[(k + 1) % NCOL];         \
      const float rt1 = (k == NCOL - 1) ? hrp.y : p1[(k + 1) % NCOL];         \
      const float up0 = __shfl_up(c1, 1, 64);   /* row i0-1 = lane-1's p1 */  \
      const float dn1 = __shfl_down(c0, 1, 64); /* row i1+1 = lane+1's p0 */  \
      const float wxr0 = __low2float(wxh[k]), wxr1 = __high2float(wxh[k]);    \
      const float wy0 = __low2float(wyh[k]), wy1 = __high2float(wyh[k]);      \
      const float wu0 = (k & 1) ? __high2float(wyu0h[k >> 1])                 \
                                : __low2float(wyu0h[k >> 1]);                 \
      const float a0 = c0 + wxl0 * (c0 - lf0) + wxr0 * (c0 - rt0) +           \
                       wu0 * (c0 - up0) + wy0 * (c0 - c1);                    \
      const float a1 = c1 + wxl1 * (c1 - lf1) + wxr1 * (c1 - rt1) +           \
                       wy0 * (c1 - c0) + wy1 * (c1 - dn1);                    \
      Ap0[k] = a0; Ap1[k] = a1;                                               \
      ACCUM;                                                                  \
      lf0 = c0; lf1 = c1; wxl0 = wxr0; wxl1 = wxr1;                           \
    }                                                                         \
  }

#define WRITE_HALO_P()                                                        \
  {                                                                           \
    *(float2*)&haloL[wv][i0] = make_float2(p0[0], p1[0]);                     \
    *(float2*)&haloR[wv][i0] = make_float2(p0[NCOL - 1], p1[NCOL - 1]);       \
  }

#define READ_HALO_REGS()                                                      \
  {                                                                           \
    hlp = *(const float2*)&haloR[wl_][i0];                                    \
    hrp = *(const float2*)&haloL[wr_][i0];                                    \
  }

__global__ __launch_bounds__(NT, 1) void GridSmoother_cg_kernel(
    const float* __restrict__ ae, const float* __restrict__ wxwy,
    float* __restrict__ out) {
  const int tid = threadIdx.x;
  const int wv = tid >> 6;
  const int lane = tid & 63;
  const int prob = blockIdx.x;  // b*16 + d
  const int bb = prob >> 4;

  const int i0 = lane << 1;
  const int i1 = i0 | 1;
  const int j0 = wv * NCOL;
  const int wl_ = (wv + NW - 1) & (NW - 1);
  const int wr_ = (wv + 1) & (NW - 1);

  const float* __restrict__ bsrc = ae + (size_t)prob * (GH * GW);
  const float* __restrict__ wxp = wxwy + (size_t)(2 * bb) * (GH * GW);
  const float* __restrict__ wyp = wxp + (GH * GW);
  float* __restrict__ outp = out + (size_t)prob * (GH * GW);

  __shared__ float haloL[NW][GH];  // published leftmost-column edge values
  __shared__ float haloR[NW][GH];  // published rightmost-column edge values
  __shared__ __align__(16) float red[2][NW];  // cross-wave reduction slots
  __shared__ float xs0[NCOL][NT];  // x for row i0, [k][tid]: conflict-free
  __shared__ float xs1[NCOL][NT];  // x for row i1

  float p0[NCOL], p1[NCOL], r0[NCOL], r1[NCOL];
  float Ap0[NCOL], Ap1[NCOL];
  float2 hlp, hrp;             // left/right neighbour p-edge (rows i0,i1)
  __half2 wxh[NCOL];           // (wx[i0][j], wx[i1][j]) right weights
  __half2 wyh[NCOL];           // (wy[i0][j], wy[i1][j]) down weights
  __half2 wyu0h[NCOL / 2];     // up weight for row i0 (lane-1's wy[i1])
  __half2 wxlh;                // left-edge weight pair (col j0-1)

  // ---- load b;  x = p = b (jax cg uses x0 = b) ----
  {
    const float2* s0 = (const float2*)(bsrc + i0 * GW + j0);
    const float2* s1 = (const float2*)(bsrc + i1 * GW + j0);
    #pragma unroll
    for (int q = 0; q < NCOL / 2; ++q) {
      float2 v0 = s0[q], v1 = s1[q];
      p0[2 * q + 0] = v0.x; p0[2 * q + 1] = v0.y;
      p1[2 * q + 0] = v1.x; p1[2 * q + 1] = v1.y;
    }
  }
  #pragma unroll
  for (int k = 0; k < NCOL; ++k) { xs0[k][tid] = p0[k]; xs1[k][tid] = p1[k]; }

  // ---- load weights (zeroed at domain boundaries), pack to fp16 ----
  {
    float wy1t[NCOL];
    const float2* a0p = (const float2*)(wxp + i0 * GW + j0);
    const float2* a1p = (const float2*)(wxp + i1 * GW + j0);
    const float2* c0p = (const float2*)(wyp + i0 * GW + j0);
    const float2* c1p = (const float2*)(wyp + i1 * GW + j0);
    #pragma unroll
    for (int q = 0; q < NCOL / 2; ++q) {
      float2 a0 = a0p[q], a1 = a1p[q], c0 = c0p[q], c1 = c1p[q];
      const float e0[2] = {a0.x, a0.y};
      const float e1[2] = {a1.x, a1.y};
      const float f0[2] = {c0.x, c0.y};
      const float f1[2] = {c1.x, c1.y};
      #pragma unroll
      for (int e = 0; e < 2; ++e) {
        const int k = 2 * q + e;
        const bool lastcol = (j0 + k == GW - 1);  // wx_e excludes col W-1
        wxh[k] = __floats2half2_rn(lastcol ? 0.f : e0[e],
                                   lastcol ? 0.f : e1[e]);
        const float wyd0 = f0[e];                        // i0 <= 126 always
        const float wyd1 = (i1 == GH - 1) ? 0.f : f1[e]; // wy_e excludes row H-1
        wyh[k] = __floats2half2_rn(wyd0, wyd1);
        wy1t[k] = wyd1;
      }
    }
    #pragma unroll
    for (int q = 0; q < NCOL / 2; ++q) {
      float ua = __shfl_up(wy1t[2 * q + 0], 1, 64);
      float ub = __shfl_up(wy1t[2 * q + 1], 1, 64);
      if (lane == 0) { ua = 0.f; ub = 0.f; }  // row 0 has no up neighbor
      wyu0h[q] = __floats2half2_rn(ua, ub);
    }
    float wl0 = 0.f, wl1 = 0.f;
    if (wv > 0) {
      wl0 = wxp[i0 * GW + (j0 - 1)];
      wl1 = wxp[i1 * GW + (j0 - 1)];
    }
    wxlh = __floats2half2_rn(wl0, wl1);
  }

  // ---- r = b - A*b ; p = r ; rr_old = <r,r> ----
  WRITE_HALO_P();            // b edges
  __syncthreads();
  READ_HALO_REGS();          // b edges -> registers
  STENCIL(;)
  float rr = 0.f;
  #pragma unroll
  for (int k = 0; k < NCOL; ++k) {
    r0[k] = p0[k] - Ap0[k];   // x == p == b here
    r1[k] = p1[k] - Ap1[k];
    rr += r0[k] * r0[k] + r1[k] * r1[k];
    p0[k] = r0[k]; p1[k] = r1[k];
  }
  rr = wave_sum(rr);
  __syncthreads();           // all waves done reading b-edge halos
  WRITE_HALO_P();            // r edges (p == r)
  if (lane == 0) red[1][wv] = rr;
  __syncthreads();
  float rr_old = 0.f;
  {
    const float4* rp = (const float4*)&red[1][0];
    #pragma unroll
    for (int q = 0; q < NW / 4; ++q) {
      float4 v = rp[q];
      rr_old += (v.x + v.y) + (v.z + v.w);
    }
  }
  READ_HALO_REGS();          // r edges == initial p edges -> registers

  // ---- CG main loop: 2 barriers / iteration ----
  #pragma unroll 1
  for (int it = 0; it < NITER; ++it) {
    float pAp = 0.f;
    STENCIL(pAp += c0 * a0 + c1 * a1;)
    pAp = wave_sum(pAp);
    if (lane == 0) red[0][wv] = pAp;
    __syncthreads();  // barrier A
    float s = 0.f;
    {
      const float4* rp = (const float4*)&red[0][0];
      #pragma unroll
      for (int q = 0; q < NW / 4; ++q) {
        float4 v = rp[q];
        s += (v.x + v.y) + (v.z + v.w);
      }
    }
    const float alpha = rr_old / fmaxf(s, 1e-37f);

    float rrn_loc = 0.f;
    #pragma unroll
    for (int k = 0; k < NCOL; ++k) {
      xs0[k][tid] = fmaf(alpha, p0[k], xs0[k][tid]);
      xs1[k][tid] = fmaf(alpha, p1[k], xs1[k][tid]);
      r0[k] = fmaf(-alpha, Ap0[k], r0[k]);
      r1[k] = fmaf(-alpha, Ap1[k], r1[k]);
      rrn_loc += r0[k] * r0[k] + r1[k] * r1[k];
    }
    if (it == NITER - 1) break;  // x is final; tail below is dead

    // publish r edges (consumed after barrier B to rebuild p-edge registers)
    *(float2*)&haloL[wv][i0] = make_float2(r0[0], r1[0]);
    *(float2*)&haloR[wv][i0] = make_float2(r0[NCOL - 1], r1[NCOL - 1]);
    rrn_loc = wave_sum(rrn_loc);
    if (lane == 0) red[1][wv] = rrn_loc;
    __syncthreads();  // barrier B
    float rrn = 0.f;
    {
      const float4* rp = (const float4*)&red[1][0];
      #pragma unroll
      for (int q = 0; q < NW / 4; ++q) {
        float4 v = rp[q];
        rrn += (v.x + v.y) + (v.z + v.w);
      }
    }
    const float beta = rrn / fmaxf(rr_old, 1e-37f);
    rr_old = rrn;

    #pragma unroll
    for (int k = 0; k < NCOL; ++k) {
      p0[k] = fmaf(beta, p0[k], r0[k]);
      p1[k] = fmaf(beta, p1[k], r1[k]);
    }
    // rebuild neighbour p-edges locally: p_edge_new = r_edge + beta*p_edge_old
    {
      const float2 hlr = *(const float2*)&haloR[wl_][i0];
      const float2 hrr = *(const float2*)&haloL[wr_][i0];
      hlp.x = fmaf(beta, hlp.x, hlr.x);
      hlp.y = fmaf(beta, hlp.y, hlr.y);
      hrp.x = fmaf(beta, hrp.x, hrr.x);
      hrp.y = fmaf(beta, hrp.y, hrr.y);
    }
  }

  // ---- store x (each thread reads only its own LDS slots; no barrier
  //      needed: xs[k][tid] was last written by this thread) ----
  {
    float2* o0 = (float2*)(outp + i0 * GW + j0);
    float2* o1 = (float2*)(outp + i1 * GW + j0);
    #pragma unroll
    for (int q = 0; q < NCOL / 2; ++q) {
      o0[q] = make_float2(xs0[2 * q + 0][tid], xs0[2 * q + 1][tid]);
      o1[q] = make_float2(xs1[2 * q + 0][tid], xs1[2 * q + 1][tid]);
    }
  }
}

extern "C" void kernel_launch(void* const* d_in, const int* in_sizes, int n_in,
                              void* d_out, int out_size, void* d_ws,
                              size_t ws_size, hipStream_t stream) {
  const float* ae = (const float*)d_in[0];      // (16,16,128,160) f32
  const float* wxwy = (const float*)d_in[1];    // (16,2,128,160) f32
  float* out = (float*)d_out;                   // (16,16,128,160) f32
  const int nprob = in_sizes[0] / (GH * GW);    // 256 systems
  GridSmoother_cg_kernel<<<dim3(nprob), dim3(NT), 0, stream>>>(ae, wxwy, out);
}

// Round 3
// 192.896 us; speedup vs baseline: 1.4561x; 1.4561x over previous
//
#include <hip/hip_runtime.h>
#include <hip/hip_fp16.h>

// GridSmoother: per-(batch,channel) CG solve of (I + graph-Laplacian) x = b
// on a 128x160 grid. One workgroup (512 threads = 8 waves) per system;
// 256 systems = 256 workgroups = exactly 1 block/CU (extra occupancy is
// unreachable, so registers are free to spend). CG vectors p/r/Ap in
// registers, x in LDS (conflict-free [k][tid] layout); wave-edge column
// halos + reduction slots in LDS.
//
// Round-4 changes vs round-3 (223 us, VGPR=64, FETCH 550 MB = spill storm):
//  * Back to NT=512/NCOL=20: at NT=1024 the backend pinned a 64-VGPR budget
//    under BOTH (1024,4) and (1024,1) -> ~40 regs/thread spilled. At NT=512
//    (512,2) measurably gave 128.
//  * amdgpu_flat_work_group_size(512,512) + amdgpu_waves_per_eu(2,2):
//    the documented LLVM attributes. min=2 waves/EU -> 512-reg file / 2 =
//    256-VGPR cap; live state ~190 regs -> ZERO spill (round 0 spilled even
//    at 128: WRITE_SIZE 35 MB vs ~21 ideal). max=2 is free: only 8 waves
//    (1 block) can ever be resident.
//  * Keeps round-1's NITER=16 (absmax identical to 32 iters) and round-3's
//    numerically-validated 2-barrier loop: p-halo rebuilt locally from
//    published r-edges (p_new = r + beta*p_old, beta block-uniform), and
//    the dead tail (rr reduce/beta/p update) skipped on the final iteration.
//
// Thread mapping: lane l holds rows 2l,2l+1 (wave spans all 128 rows);
// wave w holds columns [20w, 20w+20). Up/down neighbors: own register or
// __shfl +-1 lane. Left/right: own registers except wave edges (register
// halo pairs hlp/hrp, refreshed from LDS r-edges once per iteration).
// Weights packed fp16 (pairs per column).

#define GH 128
#define GW 160
#define NW 8
#define NCOL 20
#define NT 512
#define NITER 16

__device__ __forceinline__ float wave_sum(float v) {
  #pragma unroll
  for (int off = 32; off > 0; off >>= 1) v += __shfl_xor(v, off, 64);
  return v;
}

// Stencil: Ap = c + wxl*(c-left) + wxr*(c-right) + wyu*(c-up) + wyd*(c-down)
// Boundary terms vanish because the corresponding weight regs are zeroed.
// Left/right neighbours at wave edges come from register halos hlp/hrp.
// ACCUM may use c0,c1 (p values) and a0,a1 (Ap values).
#define STENCIL(ACCUM)                                                        \
  {                                                                           \
    float lf0 = hlp.x, lf1 = hlp.y;                                           \
    float wxl0 = __low2float(wxlh), wxl1 = __high2float(wxlh);                \
    _Pragma("unroll")                                                         \
    for (int k = 0; k < NCOL; ++k) {                                          \
      const float c0 = p0[k], c1 = p1[k];                                     \
      const float rt0 = (k == NCOL - 1) ? hrp.x : p0[(k + 1) % NCOL];         \
      const float rt1 = (k == NCOL - 1) ? hrp.y : p1[(k + 1) % NCOL];         \
      const float up0 = __shfl_up(c1, 1, 64);   /* row i0-1 = lane-1's p1 */  \
      const float dn1 = __shfl_down(c0, 1, 64); /* row i1+1 = lane+1's p0 */  \
      const float wxr0 = __low2float(wxh[k]), wxr1 = __high2float(wxh[k]);    \
      const float wy0 = __low2float(wyh[k]), wy1 = __high2float(wyh[k]);      \
      const float wu0 = (k & 1) ? __high2float(wyu0h[k >> 1])                 \
                                : __low2float(wyu0h[k >> 1]);                 \
      const float a0 = c0 + wxl0 * (c0 - lf0) + wxr0 * (c0 - rt0) +           \
                       wu0 * (c0 - up0) + wy0 * (c0 - c1);                    \
      const float a1 = c1 + wxl1 * (c1 - lf1) + wxr1 * (c1 - rt1) +           \
                       wy0 * (c1 - c0) + wy1 * (c1 - dn1);                    \
      Ap0[k] = a0; Ap1[k] = a1;                                               \
      ACCUM;                                                                  \
      lf0 = c0; lf1 = c1; wxl0 = wxr0; wxl1 = wxr1;                           \
    }                                                                         \
  }

#define WRITE_HALO_P()                                                        \
  {                                                                           \
    *(float2*)&haloL[wv][i0] = make_float2(p0[0], p1[0]);                     \
    *(float2*)&haloR[wv][i0] = make_float2(p0[NCOL - 1], p1[NCOL - 1]);       \
  }

#define READ_HALO_REGS()                                                      \
  {                                                                           \
    hlp = *(const float2*)&haloR[wl_][i0];                                    \
    hrp = *(const float2*)&haloL[wr_][i0];                                    \
  }

__global__ __attribute__((amdgpu_flat_work_group_size(NT, NT),
                          amdgpu_waves_per_eu(2, 2)))
void GridSmoother_cg_kernel(
    const float* __restrict__ ae, const float* __restrict__ wxwy,
    float* __restrict__ out) {
  const int tid = threadIdx.x;
  const int wv = tid >> 6;
  const int lane = tid & 63;
  const int prob = blockIdx.x;  // b*16 + d
  const int bb = prob >> 4;

  const int i0 = lane << 1;
  const int i1 = i0 | 1;
  const int j0 = wv * NCOL;
  const int wl_ = (wv + NW - 1) & (NW - 1);
  const int wr_ = (wv + 1) & (NW - 1);

  const float* __restrict__ bsrc = ae + (size_t)prob * (GH * GW);
  const float* __restrict__ wxp = wxwy + (size_t)(2 * bb) * (GH * GW);
  const float* __restrict__ wyp = wxp + (GH * GW);
  float* __restrict__ outp = out + (size_t)prob * (GH * GW);

  __shared__ float haloL[NW][GH];  // published leftmost-column edge values
  __shared__ float haloR[NW][GH];  // published rightmost-column edge values
  __shared__ __align__(16) float red[2][NW];  // cross-wave reduction slots
  __shared__ float xs0[NCOL][NT];  // x for row i0, [k][tid]: conflict-free
  __shared__ float xs1[NCOL][NT];  // x for row i1

  float p0[NCOL], p1[NCOL], r0[NCOL], r1[NCOL];
  float Ap0[NCOL], Ap1[NCOL];
  float2 hlp, hrp;             // left/right neighbour p-edge (rows i0,i1)
  __half2 wxh[NCOL];           // (wx[i0][j], wx[i1][j]) right weights
  __half2 wyh[NCOL];           // (wy[i0][j], wy[i1][j]) down weights
  __half2 wyu0h[NCOL / 2];     // up weight for row i0 (lane-1's wy[i1])
  __half2 wxlh;                // left-edge weight pair (col j0-1)

  // ---- load b;  x = p = b (jax cg uses x0 = b) ----
  {
    const float4* s0 = (const float4*)(bsrc + i0 * GW + j0);
    const float4* s1 = (const float4*)(bsrc + i1 * GW + j0);
    #pragma unroll
    for (int q = 0; q < NCOL / 4; ++q) {
      float4 v0 = s0[q], v1 = s1[q];
      p0[4 * q + 0] = v0.x; p0[4 * q + 1] = v0.y;
      p0[4 * q + 2] = v0.z; p0[4 * q + 3] = v0.w;
      p1[4 * q + 0] = v1.x; p1[4 * q + 1] = v1.y;
      p1[4 * q + 2] = v1.z; p1[4 * q + 3] = v1.w;
    }
  }
  #pragma unroll
  for (int k = 0; k < NCOL; ++k) { xs0[k][tid] = p0[k]; xs1[k][tid] = p1[k]; }

  // ---- load weights (zeroed at domain boundaries), pack to fp16 ----
  {
    float wy1t[NCOL];
    const float4* a0p = (const float4*)(wxp + i0 * GW + j0);
    const float4* a1p = (const float4*)(wxp + i1 * GW + j0);
    const float4* c0p = (const float4*)(wyp + i0 * GW + j0);
    const float4* c1p = (const float4*)(wyp + i1 * GW + j0);
    #pragma unroll
    for (int q = 0; q < NCOL / 4; ++q) {
      float4 a0 = a0p[q], a1 = a1p[q], c0 = c0p[q], c1 = c1p[q];
      const float e0[4] = {a0.x, a0.y, a0.z, a0.w};
      const float e1[4] = {a1.x, a1.y, a1.z, a1.w};
      const float f0[4] = {c0.x, c0.y, c0.z, c0.w};
      const float f1[4] = {c1.x, c1.y, c1.z, c1.w};
      #pragma unroll
      for (int e = 0; e < 4; ++e) {
        const int k = 4 * q + e;
        const bool lastcol = (j0 + k == GW - 1);  // wx_e excludes col W-1
        wxh[k] = __floats2half2_rn(lastcol ? 0.f : e0[e],
                                   lastcol ? 0.f : e1[e]);
        const float wyd0 = f0[e];                        // i0 <= 126 always
        const float wyd1 = (i1 == GH - 1) ? 0.f : f1[e]; // wy_e excludes row H-1
        wyh[k] = __floats2half2_rn(wyd0, wyd1);
        wy1t[k] = wyd1;
      }
    }
    #pragma unroll
    for (int q = 0; q < NCOL / 2; ++q) {
      float ua = __shfl_up(wy1t[2 * q + 0], 1, 64);
      float ub = __shfl_up(wy1t[2 * q + 1], 1, 64);
      if (lane == 0) { ua = 0.f; ub = 0.f; }  // row 0 has no up neighbor
      wyu0h[q] = __floats2half2_rn(ua, ub);
    }
    float wl0 = 0.f, wl1 = 0.f;
    if (wv > 0) {
      wl0 = wxp[i0 * GW + (j0 - 1)];
      wl1 = wxp[i1 * GW + (j0 - 1)];
    }
    wxlh = __floats2half2_rn(wl0, wl1);
  }

  // ---- r = b - A*b ; p = r ; rr_old = <r,r> ----
  WRITE_HALO_P();            // b edges
  __syncthreads();
  READ_HALO_REGS();          // b edges -> registers
  STENCIL(;)
  float rr = 0.f;
  #pragma unroll
  for (int k = 0; k < NCOL; ++k) {
    r0[k] = p0[k] - Ap0[k];   // x == p == b here
    r1[k] = p1[k] - Ap1[k];
    rr += r0[k] * r0[k] + r1[k] * r1[k];
    p0[k] = r0[k]; p1[k] = r1[k];
  }
  rr = wave_sum(rr);
  __syncthreads();           // all waves done reading b-edge halos
  WRITE_HALO_P();            // r edges (p == r)
  if (lane == 0) red[1][wv] = rr;
  __syncthreads();
  float rr_old = 0.f;
  {
    const float4* rp = (const float4*)&red[1][0];
    #pragma unroll
    for (int q = 0; q < NW / 4; ++q) {
      float4 v = rp[q];
      rr_old += (v.x + v.y) + (v.z + v.w);
    }
  }
  READ_HALO_REGS();          // r edges == initial p edges -> registers

  // ---- CG main loop: 2 barriers / iteration ----
  #pragma unroll 1
  for (int it = 0; it < NITER; ++it) {
    float pAp = 0.f;
    STENCIL(pAp += c0 * a0 + c1 * a1;)
    pAp = wave_sum(pAp);
    if (lane == 0) red[0][wv] = pAp;
    __syncthreads();  // barrier A
    float s = 0.f;
    {
      const float4* rp = (const float4*)&red[0][0];
      #pragma unroll
      for (int q = 0; q < NW / 4; ++q) {
        float4 v = rp[q];
        s += (v.x + v.y) + (v.z + v.w);
      }
    }
    const float alpha = rr_old / fmaxf(s, 1e-37f);

    float rrn_loc = 0.f;
    #pragma unroll
    for (int k = 0; k < NCOL; ++k) {
      xs0[k][tid] = fmaf(alpha, p0[k], xs0[k][tid]);
      xs1[k][tid] = fmaf(alpha, p1[k], xs1[k][tid]);
      r0[k] = fmaf(-alpha, Ap0[k], r0[k]);
      r1[k] = fmaf(-alpha, Ap1[k], r1[k]);
      rrn_loc += r0[k] * r0[k] + r1[k] * r1[k];
    }
    if (it == NITER - 1) break;  // x is final; tail below is dead

    // publish r edges (consumed after barrier B to rebuild p-edge registers)
    *(float2*)&haloL[wv][i0] = make_float2(r0[0], r1[0]);
    *(float2*)&haloR[wv][i0] = make_float2(r0[NCOL - 1], r1[NCOL - 1]);
    rrn_loc = wave_sum(rrn_loc);
    if (lane == 0) red[1][wv] = rrn_loc;
    __syncthreads();  // barrier B
    float rrn = 0.f;
    {
      const float4* rp = (const float4*)&red[1][0];
      #pragma unroll
      for (int q = 0; q < NW / 4; ++q) {
        float4 v = rp[q];
        rrn += (v.x + v.y) + (v.z + v.w);
      }
    }
    const float beta = rrn / fmaxf(rr_old, 1e-37f);
    rr_old = rrn;

    #pragma unroll
    for (int k = 0; k < NCOL; ++k) {
      p0[k] = fmaf(beta, p0[k], r0[k]);
      p1[k] = fmaf(beta, p1[k], r1[k]);
    }
    // rebuild neighbour p-edges locally: p_edge_new = r_edge + beta*p_edge_old
    {
      const float2 hlr = *(const float2*)&haloR[wl_][i0];
      const float2 hrr = *(const float2*)&haloL[wr_][i0];
      hlp.x = fmaf(beta, hlp.x, hlr.x);
      hlp.y = fmaf(beta, hlp.y, hlr.y);
      hrp.x = fmaf(beta, hrp.x, hrr.x);
      hrp.y = fmaf(beta, hrp.y, hrr.y);
    }
  }

  // ---- store x (each thread reads only its own LDS slots; no barrier
  //      needed: xs[k][tid] was last written by this thread) ----
  {
    float4* o0 = (float4*)(outp + i0 * GW + j0);
    float4* o1 = (float4*)(outp + i1 * GW + j0);
    #pragma unroll
    for (int q = 0; q < NCOL / 4; ++q) {
      o0[q] = make_float4(xs0[4 * q + 0][tid], xs0[4 * q + 1][tid],
                          xs0[4 * q + 2][tid], xs0[4 * q + 3][tid]);
      o1[q] = make_float4(xs1[4 * q + 0][tid], xs1[4 * q + 1][tid],
                          xs1[4 * q + 2][tid], xs1[4 * q + 3][tid]);
    }
  }
}

extern "C" void kernel_launch(void* const* d_in, const int* in_sizes, int n_in,
                              void* d_out, int out_size, void* d_ws,
                              size_t ws_size, hipStream_t stream) {
  const float* ae = (const float*)d_in[0];      // (16,16,128,160) f32
  const float* wxwy = (const float*)d_in[1];    // (16,2,128,160) f32
  float* out = (float*)d_out;                   // (16,16,128,160) f32
  const int nprob = in_sizes[0] / (GH * GW);    // 256 systems
  GridSmoother_cg_kernel<<<dim3(nprob), dim3(NT), 0, stream>>>(ae, wxwy, out);
}